// Round 6
// baseline (5838.455 us; speedup 1.0000x reference)
//
#include <hip/hip_runtime.h>

#define NB   128
#define TIN  256
#define DIN  64
#define HD   1024
#define G4   4096
#define TOUTC 128
#define DOUTC 128

typedef _Float16 f16x8 __attribute__((ext_vector_type(8)));
typedef float    f32x4 __attribute__((ext_vector_type(4)));

// workspace layout (bytes)
#define FLAGS_OFF 0                          // 8 grp * 4 lines * 64B = 2048
#define HPP_OFF   65536                      // 2 * 128 * 1024 f16 = 524288
#define HS2_OFF   (HPP_OFF + 524288)         // 128*128*1024 f16 = 33554432
#define WLT_OFF   (HS2_OFF + 33554432)       // 128*1024 f16 = 262144

__device__ __forceinline__ float sigm(float z) {
    return 1.0f / (1.0f + __expf(-z));
}
__device__ __forceinline__ float tanh_(float z) {
    float e = __expf(2.0f * z);
    return 1.0f - 2.0f / (e + 1.0f);
}

// 8x coherent (LLC-direct) 16B loads from one base address, single waitcnt.
// sc0 sc1 => bypass L1 and L2, read the device coherence point (proven r4).
__device__ __forceinline__ void load_h8(const _Float16* p, f16x8 av[8]) {
    asm volatile(
        "global_load_dwordx4 %0, %8, off sc0 sc1\n\t"
        "global_load_dwordx4 %1, %8, off offset:64 sc0 sc1\n\t"
        "global_load_dwordx4 %2, %8, off offset:128 sc0 sc1\n\t"
        "global_load_dwordx4 %3, %8, off offset:192 sc0 sc1\n\t"
        "global_load_dwordx4 %4, %8, off offset:256 sc0 sc1\n\t"
        "global_load_dwordx4 %5, %8, off offset:320 sc0 sc1\n\t"
        "global_load_dwordx4 %6, %8, off offset:384 sc0 sc1\n\t"
        "global_load_dwordx4 %7, %8, off offset:448 sc0 sc1\n\t"
        "s_waitcnt vmcnt(0)"
        : "=&v"(av[0]), "=&v"(av[1]), "=&v"(av[2]), "=&v"(av[3]),
          "=&v"(av[4]), "=&v"(av[5]), "=&v"(av[6]), "=&v"(av[7])
        : "v"(p) : "memory");
}

__device__ __forceinline__ int flag_ld(const int* slot) {
    int v;
    asm volatile("global_load_dword %0, %1, off sc0 sc1\n\ts_waitcnt vmcnt(0)"
                 : "=v"(v) : "v"(slot) : "memory");
    return v;
}

__global__ void k_init(const float* __restrict__ Wlin, unsigned char* __restrict__ ws)
{
    int tid = blockIdx.x * blockDim.x + threadIdx.x;
    if (tid < 512) ((int*)(ws + FLAGS_OFF))[tid] = 0;   // packed flag lines
    _Float16* wlt = (_Float16*)(ws + WLT_OFF);
    for (int i = tid; i < DOUTC * HD; i += gridDim.x * blockDim.x) {
        int d = i >> 10, k = i & 1023;
        wlt[i] = (_Float16)Wlin[k * DOUTC + d];   // WlinT[d][k]
    }
}

// Persistent recurrent kernel: 256 WGs x 512 threads, 1 WG/CU.
// group g = gid&7, 16 batches [16g,16g+16). WG p = gid>>3 owns 32 hidden
// units [32p,32p+32). 8 waves: (t = unit-tile half, ks = K-quarter).
// Wh frags live in registers. All cross-WG comm at the LLC (sc0 sc1).
// Flags: per group 4 lines (one per K-quarter); line g*4+q holds 16 ints,
// int (p&7)*2+t, single-writer dword stores, consumers poll one line/wave.
__global__ __launch_bounds__(512, 2)
void k_lstm(const float* __restrict__ x,   const float* __restrict__ Wi1,
            const float* __restrict__ Wh1, const float* __restrict__ b1,
            const float* __restrict__ Wi2, const float* __restrict__ Wh2,
            const float* __restrict__ b2,  unsigned char* __restrict__ ws)
{
    int* flagbase   = (int*)(ws + FLAGS_OFF);
    _Float16* hpp   = (_Float16*)(ws + HPP_OFF);
    _Float16* hs2   = (_Float16*)(ws + HS2_OFF);

    const int tid  = threadIdx.x;
    const int lane = tid & 63;
    const int w    = tid >> 6;
    const int t    = w & 1;        // unit-tile half (16 units)
    const int ks   = w >> 1;       // K-quarter
    const int gid  = blockIdx.x;
    const int g    = gid & 7;      // group
    const int p    = gid >> 3;     // 0..31 within group
    const int u0   = p * 32 + t * 16;   // this wave's 16-unit tile base
    const int l15  = lane & 15;
    const int lhi  = lane >> 4;
    const int grow = g * 16 + l15; // batch row for MFMA A operand
    const int kq   = ks << 8;      // K-quarter base

    __shared__ float parts[2][3][2][4][16][17]; // [parity][ks-1][t][gate][unit][row]
    __shared__ float xg2s[2][4][16][17];        // [t][gate][unit][row]

    f16x8 wB[8][4];      // Wh frags: [kk][gate]
    f16x8 wX[2][4];      // Wi1 frags (ks==1 waves)
    float bias4[4];
    f32x4 cst = {0.f, 0.f, 0.f, 0.f};

    // ---- load Wh1 fragments into registers ----
    {
        const float* W = Wh1;
        #pragma unroll
        for (int kk = 0; kk < 8; ++kk)
        #pragma unroll
        for (int ct = 0; ct < 4; ++ct) {
            const int col = ct * HD + u0 + l15;
            const int kb  = kq + kk * 32 + lhi * 8;
            f16x8 v;
            #pragma unroll
            for (int e = 0; e < 8; ++e) v[e] = (_Float16)W[(kb + e) * G4 + col];
            wB[kk][ct] = v;
        }
    }
    if (ks == 1) {
        #pragma unroll
        for (int kk = 0; kk < 2; ++kk)
        #pragma unroll
        for (int ct = 0; ct < 4; ++ct) {
            const int col = ct * HD + u0 + l15;
            const int kb  = kk * 32 + lhi * 8;
            f16x8 v;
            #pragma unroll
            for (int e = 0; e < 8; ++e) v[e] = (_Float16)Wi1[(kb + e) * G4 + col];
            wX[kk][ct] = v;
        }
    }
    if (ks == 0) {
        #pragma unroll
        for (int ct = 0; ct < 4; ++ct) bias4[ct] = b1[ct * HD + u0 + l15];
    }

    // consumer (quarter ks) needs producers p' in [8ks,8ks+8) x t' in {0,1}
    // = the 16 ints of line g*4+ks; one int per lane (4-replicated).
    const int* pollslot = flagbase + (g * 4 + ks) * 16 + (lane & 15);
    int* myslot         = flagbase + (g * 4 + (p >> 3)) * 16 + ((p & 7) * 2 + t);

    bool dead = false;   // spin bailout latch (anti-hang insurance)

    #pragma unroll 1
    for (int s = 0; s < 384; ++s) {
        if (s == 256) {
            // ---------- xg2 = hT @ Wi2 + b2 (once), swap weights to Wh2 ----------
            if (!dead) {
                long it = 0;
                while (!__all(flag_ld(pollslot) >= 256)) {
                    __builtin_amdgcn_s_sleep(1);
                    if (++it > (1L << 21)) { dead = true; break; }
                }
            }
            f32x4 acc[4];
            #pragma unroll
            for (int ct = 0; ct < 4; ++ct) acc[ct] = {0.f,0.f,0.f,0.f};
            const _Float16* hprev = hpp + 1 * NB * HD;   // h_255 in parity 1
            f16x8 av[8];
            load_h8(hprev + grow * HD + kq + lhi * 8, av);
            #pragma unroll
            for (int kk = 0; kk < 8; ++kk) {
                const int kb = kq + kk * 32 + lhi * 8;
                #pragma unroll
                for (int ct = 0; ct < 4; ++ct) {
                    const int col = ct * HD + u0 + l15;
                    f16x8 bb;
                    #pragma unroll
                    for (int e = 0; e < 8; ++e) bb[e] = (_Float16)Wi2[(kb + e) * G4 + col];
                    acc[ct] = __builtin_amdgcn_mfma_f32_16x16x32_f16(av[kk], bb, acc[ct], 0, 0, 0);
                }
            }
            if (ks > 0) {
                #pragma unroll
                for (int ct = 0; ct < 4; ++ct)
                #pragma unroll
                for (int i = 0; i < 4; ++i)
                    parts[0][ks - 1][t][ct][l15][lhi * 4 + i] = acc[ct][i];
            }
            __syncthreads();
            if (ks == 0) {
                #pragma unroll
                for (int ct = 0; ct < 4; ++ct) {
                    #pragma unroll
                    for (int j = 0; j < 3; ++j)
                    #pragma unroll
                    for (int i = 0; i < 4; ++i)
                        acc[ct][i] += parts[0][j][t][ct][l15][lhi * 4 + i];
                    const float bv = b2[ct * HD + u0 + l15];
                    #pragma unroll
                    for (int i = 0; i < 4; ++i)
                        xg2s[t][ct][l15][lhi * 4 + i] = acc[ct][i] + bv;
                }
            }
            __syncthreads();   // protects parts[0] reuse and xg2s reads
            // reload register weights with Wh2
            {
                const float* W = Wh2;
                #pragma unroll
                for (int kk = 0; kk < 8; ++kk)
                #pragma unroll
                for (int ct = 0; ct < 4; ++ct) {
                    const int col = ct * HD + u0 + l15;
                    const int kb  = kq + kk * 32 + lhi * 8;
                    f16x8 v;
                    #pragma unroll
                    for (int e = 0; e < 8; ++e) v[e] = (_Float16)W[(kb + e) * G4 + col];
                    wB[kk][ct] = v;
                }
            }
        }

        const int  par = s & 1;
        const bool l2  = (s >= 256);

        // ---- wait for h_{s-1}: this wave's K-quarter (one flag line) ----
        if (s > 0 && !dead) {
            long it = 0;
            while (!__all(flag_ld(pollslot) >= s)) {
                __builtin_amdgcn_s_sleep(1);
                if (++it > (1L << 21)) { dead = true; break; }
            }
        }

        // ---- accumulator init: bias (L1) / xg2 (L2) on ks0, zero elsewhere ----
        f32x4 acc[4];
        if (ks == 0) {
            if (!l2) {
                #pragma unroll
                for (int ct = 0; ct < 4; ++ct)
                    acc[ct] = {bias4[ct], bias4[ct], bias4[ct], bias4[ct]};
            } else {
                #pragma unroll
                for (int ct = 0; ct < 4; ++ct)
                #pragma unroll
                for (int i = 0; i < 4; ++i)
                    acc[ct][i] = xg2s[t][ct][l15][lhi * 4 + i];
            }
        } else {
            #pragma unroll
            for (int ct = 0; ct < 4; ++ct) acc[ct] = {0.f,0.f,0.f,0.f};
        }

        // ---- h_{s-1} @ Wh (register-resident B, LLC-coherent A) ----
        if (s > 0) {
            const _Float16* hprev = hpp + ((s + 1) & 1) * NB * HD;
            f16x8 av[8];
            load_h8(hprev + grow * HD + kq + lhi * 8, av);
            #pragma unroll
            for (int kk = 0; kk < 8; ++kk) {
                #pragma unroll
                for (int ct = 0; ct < 4; ++ct)
                    acc[ct] = __builtin_amdgcn_mfma_f32_16x16x32_f16(av[kk], wB[kk][ct], acc[ct], 0, 0, 0);
            }
        }
        // ---- x_t @ Wi1 (layer 1, ks1 waves) ----
        if (!l2 && ks == 1) {
            const float* xp = x + (grow * TIN + s) * DIN;
            #pragma unroll
            for (int kk = 0; kk < 2; ++kk) {
                const int kb = kk * 32 + lhi * 8;
                f32x4 x0 = *(const f32x4*)(xp + kb);
                f32x4 x1 = *(const f32x4*)(xp + kb + 4);
                f16x8 a;
                #pragma unroll
                for (int e = 0; e < 4; ++e) { a[e] = (_Float16)x0[e]; a[e + 4] = (_Float16)x1[e]; }
                #pragma unroll
                for (int ct = 0; ct < 4; ++ct)
                    acc[ct] = __builtin_amdgcn_mfma_f32_16x16x32_f16(a, wX[kk][ct], acc[ct], 0, 0, 0);
            }
        }

        // ---- exchange K-quarter partials through LDS ----
        if (ks > 0) {
            #pragma unroll
            for (int ct = 0; ct < 4; ++ct)
            #pragma unroll
            for (int i = 0; i < 4; ++i)
                parts[par][ks - 1][t][ct][l15][lhi * 4 + i] = acc[ct][i];
        }
        __syncthreads();

        // ---- ks0: reduce + gates + state update + publish ----
        if (ks == 0) {
            #pragma unroll
            for (int ct = 0; ct < 4; ++ct)
            #pragma unroll
            for (int j = 0; j < 3; ++j)
            #pragma unroll
            for (int i = 0; i < 4; ++i)
                acc[ct][i] += parts[par][j][t][ct][l15][lhi * 4 + i];

            _Float16* hout = hpp + par * NB * HD;
            unsigned hb[4];
            #pragma unroll
            for (int i = 0; i < 4; ++i) {
                const float ig = sigm(acc[0][i]);
                const float fg = sigm(acc[1][i]);
                const float gg = tanh_(acc[2][i]);
                const float og = sigm(acc[3][i]);
                const float cn = fg * cst[i] + ig * gg;
                cst[i] = cn;
                const float hn = og * tanh_(cn);
                const _Float16 hf = (_Float16)hn;
                hb[i] = (unsigned)__builtin_bit_cast(unsigned short, hf);
                const int row = g * 16 + lhi * 4 + i;
                if (l2) hs2[((s - 256) * NB + row) * HD + u0 + l15] = hf;
            }
            _Float16* p01 = hout + (g * 16 + lhi * 4) * HD + u0 + l15;
            _Float16* p23 = p01 + 2 * HD;
            // write-through stores to the coherence point + completion wait,
            // then the single-writer flag dword (also write-through).
            asm volatile(
                "global_store_short %0, %2, off sc0 sc1\n\t"
                "global_store_short %0, %3, off offset:2048 sc0 sc1\n\t"
                "global_store_short %1, %4, off sc0 sc1\n\t"
                "global_store_short %1, %5, off offset:2048 sc0 sc1\n\t"
                "s_waitcnt vmcnt(0)"
                :: "v"(p01), "v"(p23), "v"(hb[0]), "v"(hb[1]), "v"(hb[2]), "v"(hb[3])
                : "memory");
            if (lane == 0) {
                const int val = s + 1;
                asm volatile("global_store_dword %0, %1, off sc0 sc1"
                             :: "v"(myslot), "v"(val) : "memory");
            }
        }
    }
}

// out[b][t][d] = hs2[t][b][:] @ Wlin + blin ; grid = 128 t x 2 d-halves
__global__ __launch_bounds__(512, 2)
void k_out(const unsigned char* __restrict__ ws, const float* __restrict__ blin,
           float* __restrict__ out)
{
    const _Float16* hs2 = (const _Float16*)(ws + HS2_OFF);
    const _Float16* wlt = (const _Float16*)(ws + WLT_OFF);
    const int tid  = threadIdx.x;
    const int lane = tid & 63;
    const int l15  = lane & 15, lhi = lane >> 4;
    const int w    = tid >> 6;
    const int wb   = w & 3, wd = w >> 2;
    const int t    = blockIdx.x >> 1;
    const int dh   = blockIdx.x & 1;
    const int b0   = wb * 32;
    const int d0   = dh * 64 + wd * 32;

    f32x4 acc[2][2];
    #pragma unroll
    for (int a_ = 0; a_ < 2; ++a_)
    #pragma unroll
    for (int b_ = 0; b_ < 2; ++b_) acc[a_][b_] = {0.f,0.f,0.f,0.f};

    #pragma unroll 4
    for (int kk = 0; kk < 32; ++kk) {
        const int kb = kk * 32 + lhi * 8;
        f16x8 a0 = *(const f16x8*)(hs2 + (t * NB + b0 + l15) * HD + kb);
        f16x8 a1 = *(const f16x8*)(hs2 + (t * NB + b0 + 16 + l15) * HD + kb);
        f16x8 q0 = *(const f16x8*)(wlt + (d0 + l15) * HD + kb);
        f16x8 q1 = *(const f16x8*)(wlt + (d0 + 16 + l15) * HD + kb);
        acc[0][0] = __builtin_amdgcn_mfma_f32_16x16x32_f16(a0, q0, acc[0][0], 0, 0, 0);
        acc[0][1] = __builtin_amdgcn_mfma_f32_16x16x32_f16(a0, q1, acc[0][1], 0, 0, 0);
        acc[1][0] = __builtin_amdgcn_mfma_f32_16x16x32_f16(a1, q0, acc[1][0], 0, 0, 0);
        acc[1][1] = __builtin_amdgcn_mfma_f32_16x16x32_f16(a1, q1, acc[1][1], 0, 0, 0);
    }
    #pragma unroll
    for (int bi = 0; bi < 2; ++bi)
    #pragma unroll
    for (int dj = 0; dj < 2; ++dj) {
        const int dcol = d0 + dj * 16 + l15;
        const float bv = blin[dcol];
        #pragma unroll
        for (int i = 0; i < 4; ++i) {
            const int row = b0 + bi * 16 + lhi * 4 + i;
            out[(row * TOUTC + t) * DOUTC + dcol] = acc[bi][dj][i] + bv;
        }
    }
}

extern "C" void kernel_launch(void* const* d_in, const int* in_sizes, int n_in,
                              void* d_out, int out_size, void* d_ws, size_t ws_size,
                              hipStream_t stream)
{
    const float* x    = (const float*)d_in[0];
    const float* Wi1  = (const float*)d_in[1];
    const float* Wh1  = (const float*)d_in[2];
    const float* b1   = (const float*)d_in[3];
    const float* Wi2  = (const float*)d_in[4];
    const float* Wh2  = (const float*)d_in[5];
    const float* b2   = (const float*)d_in[6];
    const float* Wlin = (const float*)d_in[7];
    const float* blin = (const float*)d_in[8];
    unsigned char* ws = (unsigned char*)d_ws;
    float* out = (float*)d_out;

    k_init<<<256, 256, 0, stream>>>(Wlin, ws);
    k_lstm<<<256, 512, 0, stream>>>(x, Wi1, Wh1, b1, Wi2, Wh2, b2, ws);
    k_out <<<256, 512, 0, stream>>>(ws, blin, out);
}

// Round 8
// 3367.123 us; speedup vs baseline: 1.7340x; 1.7340x over previous
//
#include <hip/hip_runtime.h>

#define NB   128
#define TIN  256
#define DIN  64
#define HD   1024
#define G4   4096
#define TOUTC 128
#define DOUTC 128

typedef _Float16 f16x8 __attribute__((ext_vector_type(8)));
typedef float    f32x4 __attribute__((ext_vector_type(4)));

// workspace layout (bytes)
#define FLAGS_OFF 0                          // 8 grp * 64 ints (4 lines) = 2048
#define HPP_OFF   65536                      // 2 * 128 * 1024 f16 = 524288
#define HS2_OFF   (HPP_OFF + 524288)         // 128*128*1024 f16 = 33554432
#define WLT_OFF   (HS2_OFF + 33554432)       // 128*1024 f16 = 262144

__device__ __forceinline__ float sigm(float z) {
    return 1.0f / (1.0f + __expf(-z));
}
__device__ __forceinline__ float tanh_(float z) {
    float e = __expf(2.0f * z);
    return 1.0f - 2.0f / (e + 1.0f);
}

// 8x coherent (device-scope) 16B loads from one base address, single waitcnt.
// sc0 sc1 => bypass L1 and L2, read the device coherence point (proven r4/r6).
__device__ __forceinline__ void load_h8(const _Float16* p, f16x8 av[8]) {
    asm volatile(
        "global_load_dwordx4 %0, %8, off sc0 sc1\n\t"
        "global_load_dwordx4 %1, %8, off offset:64 sc0 sc1\n\t"
        "global_load_dwordx4 %2, %8, off offset:128 sc0 sc1\n\t"
        "global_load_dwordx4 %3, %8, off offset:192 sc0 sc1\n\t"
        "global_load_dwordx4 %4, %8, off offset:256 sc0 sc1\n\t"
        "global_load_dwordx4 %5, %8, off offset:320 sc0 sc1\n\t"
        "global_load_dwordx4 %6, %8, off offset:384 sc0 sc1\n\t"
        "global_load_dwordx4 %7, %8, off offset:448 sc0 sc1\n\t"
        "s_waitcnt vmcnt(0)"
        : "=&v"(av[0]), "=&v"(av[1]), "=&v"(av[2]), "=&v"(av[3]),
          "=&v"(av[4]), "=&v"(av[5]), "=&v"(av[6]), "=&v"(av[7])
        : "v"(p) : "memory");
}

__global__ void k_init(const float* __restrict__ Wlin, unsigned char* __restrict__ ws)
{
    int tid = blockIdx.x * blockDim.x + threadIdx.x;
    if (tid < 512) ((int*)(ws + FLAGS_OFF))[tid] = 0;   // flag block (8 grp * 64)
    _Float16* wlt = (_Float16*)(ws + WLT_OFF);
    for (int i = tid; i < DOUTC * HD; i += gridDim.x * blockDim.x) {
        int d = i >> 10, k = i & 1023;
        wlt[i] = (_Float16)Wlin[k * DOUTC + d];   // WlinT[d][k]
    }
}

// Persistent recurrent kernel: 256 WGs x 512 threads, 1 WG/CU.
// group g = gid&7, 16 batches [16g,16g+16). WG p = gid>>3 owns 32 hidden
// units [32p,32p+32). 8 waves: (t = unit-tile half, ks = K-quarter).
// Wh frags in registers. All cross-WG comm at the LLC (sc0 sc1, proven r6).
// Sync: ONE poller wave (w==0) per WG reads the group's 64-int flag block
// (lane i -> int i) and broadcasts readiness via an LDS token; the other 7
// waves spin on LDS only (no fabric traffic). Producers publish single-writer
// dword slots: int (p>>3)*16 + (p&7)*2 + t of the group block.
__global__ __launch_bounds__(512, 2)
void k_lstm(const float* __restrict__ x,   const float* __restrict__ Wi1,
            const float* __restrict__ Wh1, const float* __restrict__ b1,
            const float* __restrict__ Wi2, const float* __restrict__ Wh2,
            const float* __restrict__ b2,  unsigned char* __restrict__ ws)
{
    int* flagbase   = (int*)(ws + FLAGS_OFF);
    _Float16* hpp   = (_Float16*)(ws + HPP_OFF);
    _Float16* hs2   = (_Float16*)(ws + HS2_OFF);

    const int tid  = threadIdx.x;
    const int lane = tid & 63;
    const int w    = tid >> 6;
    const int t    = w & 1;        // unit-tile half (16 units)
    const int ks   = w >> 1;       // K-quarter
    const int gid  = blockIdx.x;
    const int g    = gid & 7;      // group
    const int p    = gid >> 3;     // 0..31 within group
    const int u0   = p * 32 + t * 16;   // this wave's 16-unit tile base
    const int l15  = lane & 15;
    const int lhi  = lane >> 4;
    const int grow = g * 16 + l15; // batch row for MFMA A operand
    const int kq   = ks << 8;      // K-quarter base

    __shared__ float parts[2][3][2][4][16][17]; // [parity][ks-1][t][gate][unit][row]
    __shared__ float xg2s[2][4][16][17];        // [t][gate][unit][row]
    __shared__ int   token_s;                   // highest step whose h_{s-1} is ready

    if (tid == 0) token_s = 0;
    __syncthreads();
    volatile int* tokp = &token_s;

    f16x8 wB[8][4];      // Wh frags: [kk][gate]
    f16x8 wX[2][4];      // Wi1 frags (ks==1 waves)
    float bias4[4];
    f32x4 cst = {0.f, 0.f, 0.f, 0.f};

    // ---- load Wh1 fragments into registers ----
    {
        const float* W = Wh1;
        #pragma unroll
        for (int kk = 0; kk < 8; ++kk)
        #pragma unroll
        for (int ct = 0; ct < 4; ++ct) {
            const int col = ct * HD + u0 + l15;
            const int kb  = kq + kk * 32 + lhi * 8;
            f16x8 v;
            #pragma unroll
            for (int e = 0; e < 8; ++e) v[e] = (_Float16)W[(kb + e) * G4 + col];
            wB[kk][ct] = v;
        }
    }
    if (ks == 1) {
        #pragma unroll
        for (int kk = 0; kk < 2; ++kk)
        #pragma unroll
        for (int ct = 0; ct < 4; ++ct) {
            const int col = ct * HD + u0 + l15;
            const int kb  = kk * 32 + lhi * 8;
            f16x8 v;
            #pragma unroll
            for (int e = 0; e < 8; ++e) v[e] = (_Float16)Wi1[(kb + e) * G4 + col];
            wX[kk][ct] = v;
        }
    }
    if (ks == 0) {
        #pragma unroll
        for (int ct = 0; ct < 4; ++ct) bias4[ct] = b1[ct * HD + u0 + l15];
    }

    const int* pollbase = flagbase + g * 64 + lane;                       // poller wave
    int* myslot         = flagbase + g * 64 + (p >> 3) * 16 + (p & 7) * 2 + t;

    int  tok  = 0;       // poller-wave local mirror of token_s
    bool dead = false;   // spin bailout latch (anti-hang insurance)

    // wait until h_{target-1} is published by all 32 WGs of the group
    auto WAIT = [&](int target) {
        if (w == 0) {
            if (!dead && tok < target) {
                long it = 0;
                for (;;) {
                    int v;
                    asm volatile("global_load_dword %0, %1, off sc0 sc1\n\ts_waitcnt vmcnt(0)"
                                 : "=v"(v) : "v"(pollbase) : "memory");
                    if (__all(v >= target)) break;
                    __builtin_amdgcn_s_sleep(1);
                    if (++it > (1L << 21)) { dead = true; break; }
                }
            }
            if (tok < target) { tok = target; if (lane == 0) *tokp = target; }
        } else {
            if (!dead) {
                long it = 0;
                while (*tokp < target) {
                    __builtin_amdgcn_s_sleep(1);
                    if (++it > (1L << 24)) { dead = true; break; }
                }
            }
        }
    };

    #pragma unroll 1
    for (int s = 0; s < 384; ++s) {
        if (s == 256) {
            // ---------- xg2 = hT @ Wi2 + b2 (once), swap weights to Wh2 ----------
            WAIT(256);
            f32x4 acc[4];
            #pragma unroll
            for (int ct = 0; ct < 4; ++ct) acc[ct] = {0.f,0.f,0.f,0.f};
            const _Float16* hprev = hpp + 1 * NB * HD;   // h_255 in parity 1
            f16x8 av[8];
            load_h8(hprev + grow * HD + kq + lhi * 8, av);
            #pragma unroll
            for (int kk = 0; kk < 8; ++kk) {
                const int kb = kq + kk * 32 + lhi * 8;
                #pragma unroll
                for (int ct = 0; ct < 4; ++ct) {
                    const int col = ct * HD + u0 + l15;
                    f16x8 bb;
                    #pragma unroll
                    for (int e = 0; e < 8; ++e) bb[e] = (_Float16)Wi2[(kb + e) * G4 + col];
                    acc[ct] = __builtin_amdgcn_mfma_f32_16x16x32_f16(av[kk], bb, acc[ct], 0, 0, 0);
                }
            }
            if (ks > 0) {
                #pragma unroll
                for (int ct = 0; ct < 4; ++ct)
                #pragma unroll
                for (int i = 0; i < 4; ++i)
                    parts[0][ks - 1][t][ct][l15][lhi * 4 + i] = acc[ct][i];
            }
            __syncthreads();
            if (ks == 0) {
                #pragma unroll
                for (int ct = 0; ct < 4; ++ct) {
                    #pragma unroll
                    for (int j = 0; j < 3; ++j)
                    #pragma unroll
                    for (int i = 0; i < 4; ++i)
                        acc[ct][i] += parts[0][j][t][ct][l15][lhi * 4 + i];
                    const float bv = b2[ct * HD + u0 + l15];
                    #pragma unroll
                    for (int i = 0; i < 4; ++i)
                        xg2s[t][ct][l15][lhi * 4 + i] = acc[ct][i] + bv;
                }
            }
            __syncthreads();   // protects parts[0] reuse and xg2s reads
            // reload register weights with Wh2
            {
                const float* W = Wh2;
                #pragma unroll
                for (int kk = 0; kk < 8; ++kk)
                #pragma unroll
                for (int ct = 0; ct < 4; ++ct) {
                    const int col = ct * HD + u0 + l15;
                    const int kb  = kq + kk * 32 + lhi * 8;
                    f16x8 v;
                    #pragma unroll
                    for (int e = 0; e < 8; ++e) v[e] = (_Float16)W[(kb + e) * G4 + col];
                    wB[kk][ct] = v;
                }
            }
        }

        const int  par = s & 1;
        const bool l2  = (s >= 256);

        // ---- wait for h_{s-1} (poller wave + LDS token broadcast) ----
        if (s > 0) WAIT(s);

        // ---- accumulator init: bias (L1) / xg2 (L2) on ks0, zero elsewhere ----
        f32x4 acc[4];
        if (ks == 0) {
            if (!l2) {
                #pragma unroll
                for (int ct = 0; ct < 4; ++ct)
                    acc[ct] = {bias4[ct], bias4[ct], bias4[ct], bias4[ct]};
            } else {
                #pragma unroll
                for (int ct = 0; ct < 4; ++ct)
                #pragma unroll
                for (int i = 0; i < 4; ++i)
                    acc[ct][i] = xg2s[t][ct][l15][lhi * 4 + i];
            }
        } else {
            #pragma unroll
            for (int ct = 0; ct < 4; ++ct) acc[ct] = {0.f,0.f,0.f,0.f};
        }

        // ---- h_{s-1} @ Wh (register-resident B, LLC-coherent A) ----
        if (s > 0) {
            const _Float16* hprev = hpp + ((s + 1) & 1) * NB * HD;
            f16x8 av[8];
            load_h8(hprev + grow * HD + kq + lhi * 8, av);
            #pragma unroll
            for (int kk = 0; kk < 8; ++kk) {
                #pragma unroll
                for (int ct = 0; ct < 4; ++ct)
                    acc[ct] = __builtin_amdgcn_mfma_f32_16x16x32_f16(av[kk], wB[kk][ct], acc[ct], 0, 0, 0);
            }
        }
        // ---- x_t @ Wi1 (layer 1, ks1 waves) ----
        if (!l2 && ks == 1) {
            const float* xp = x + (grow * TIN + s) * DIN;
            #pragma unroll
            for (int kk = 0; kk < 2; ++kk) {
                const int kb = kk * 32 + lhi * 8;
                f32x4 x0 = *(const f32x4*)(xp + kb);
                f32x4 x1 = *(const f32x4*)(xp + kb + 4);
                f16x8 a;
                #pragma unroll
                for (int e = 0; e < 4; ++e) { a[e] = (_Float16)x0[e]; a[e + 4] = (_Float16)x1[e]; }
                #pragma unroll
                for (int ct = 0; ct < 4; ++ct)
                    acc[ct] = __builtin_amdgcn_mfma_f32_16x16x32_f16(a, wX[kk][ct], acc[ct], 0, 0, 0);
            }
        }

        // ---- exchange K-quarter partials through LDS ----
        if (ks > 0) {
            #pragma unroll
            for (int ct = 0; ct < 4; ++ct)
            #pragma unroll
            for (int i = 0; i < 4; ++i)
                parts[par][ks - 1][t][ct][l15][lhi * 4 + i] = acc[ct][i];
        }
        __syncthreads();

        // ---- ks0: reduce + gates + state update + publish ----
        if (ks == 0) {
            #pragma unroll
            for (int ct = 0; ct < 4; ++ct)
            #pragma unroll
            for (int j = 0; j < 3; ++j)
            #pragma unroll
            for (int i = 0; i < 4; ++i)
                acc[ct][i] += parts[par][j][t][ct][l15][lhi * 4 + i];

            _Float16* hout = hpp + par * NB * HD;
            unsigned  hb[4];
            _Float16  hfs[4];
            #pragma unroll
            for (int i = 0; i < 4; ++i) {
                const float ig = sigm(acc[0][i]);
                const float fg = sigm(acc[1][i]);
                const float gg = tanh_(acc[2][i]);
                const float og = sigm(acc[3][i]);
                const float cn = fg * cst[i] + ig * gg;
                cst[i] = cn;
                const float hn = og * tanh_(cn);
                const _Float16 hf = (_Float16)hn;
                hfs[i] = hf;
                hb[i] = (unsigned)__builtin_bit_cast(unsigned short, hf);
            }
            _Float16* p01 = hout + (g * 16 + lhi * 4) * HD + u0 + l15;
            _Float16* p23 = p01 + 2 * HD;
            // write-through stores to the coherence point + completion wait,
            // then the single-writer flag dword (also write-through).
            asm volatile(
                "global_store_short %0, %2, off sc0 sc1\n\t"
                "global_store_short %0, %3, off offset:2048 sc0 sc1\n\t"
                "global_store_short %1, %4, off sc0 sc1\n\t"
                "global_store_short %1, %5, off offset:2048 sc0 sc1\n\t"
                "s_waitcnt vmcnt(0)"
                :: "v"(p01), "v"(p23), "v"(hb[0]), "v"(hb[1]), "v"(hb[2]), "v"(hb[3])
                : "memory");
            if (lane == 0) {
                const int val = s + 1;
                asm volatile("global_store_dword %0, %1, off sc0 sc1"
                             :: "v"(myslot), "v"(val) : "memory");
            }
            // hs2 writes AFTER the publish — keeps their ack latency off the
            // critical chain (they share the vmcnt counter with hpp stores).
            if (l2) {
                #pragma unroll
                for (int i = 0; i < 4; ++i) {
                    const int row = g * 16 + lhi * 4 + i;
                    hs2[((s - 256) * NB + row) * HD + u0 + l15] = hfs[i];
                }
            }
        }
    }
}

// out[b][t][d] = hs2[t][b][:] @ Wlin + blin ; grid = 128 t x 2 d-halves
__global__ __launch_bounds__(512, 2)
void k_out(const unsigned char* __restrict__ ws, const float* __restrict__ blin,
           float* __restrict__ out)
{
    const _Float16* hs2 = (const _Float16*)(ws + HS2_OFF);
    const _Float16* wlt = (const _Float16*)(ws + WLT_OFF);
    const int tid  = threadIdx.x;
    const int lane = tid & 63;
    const int l15  = lane & 15, lhi = lane >> 4;
    const int w    = tid >> 6;
    const int wb   = w & 3, wd = w >> 2;
    const int t    = blockIdx.x >> 1;
    const int dh   = blockIdx.x & 1;
    const int b0   = wb * 32;
    const int d0   = dh * 64 + wd * 32;

    f32x4 acc[2][2];
    #pragma unroll
    for (int a_ = 0; a_ < 2; ++a_)
    #pragma unroll
    for (int b_ = 0; b_ < 2; ++b_) acc[a_][b_] = {0.f,0.f,0.f,0.f};

    #pragma unroll 4
    for (int kk = 0; kk < 32; ++kk) {
        const int kb = kk * 32 + lhi * 8;
        f16x8 a0 = *(const f16x8*)(hs2 + (t * NB + b0 + l15) * HD + kb);
        f16x8 a1 = *(const f16x8*)(hs2 + (t * NB + b0 + 16 + l15) * HD + kb);
        f16x8 q0 = *(const f16x8*)(wlt + (d0 + l15) * HD + kb);
        f16x8 q1 = *(const f16x8*)(wlt + (d0 + 16 + l15) * HD + kb);
        acc[0][0] = __builtin_amdgcn_mfma_f32_16x16x32_f16(a0, q0, acc[0][0], 0, 0, 0);
        acc[0][1] = __builtin_amdgcn_mfma_f32_16x16x32_f16(a0, q1, acc[0][1], 0, 0, 0);
        acc[1][0] = __builtin_amdgcn_mfma_f32_16x16x32_f16(a1, q0, acc[1][0], 0, 0, 0);
        acc[1][1] = __builtin_amdgcn_mfma_f32_16x16x32_f16(a1, q1, acc[1][1], 0, 0, 0);
    }
    #pragma unroll
    for (int bi = 0; bi < 2; ++bi)
    #pragma unroll
    for (int dj = 0; dj < 2; ++dj) {
        const int dcol = d0 + dj * 16 + l15;
        const float bv = blin[dcol];
        #pragma unroll
        for (int i = 0; i < 4; ++i) {
            const int row = b0 + bi * 16 + lhi * 4 + i;
            out[(row * TOUTC + t) * DOUTC + dcol] = acc[bi][dj][i] + bv;
        }
    }
}

extern "C" void kernel_launch(void* const* d_in, const int* in_sizes, int n_in,
                              void* d_out, int out_size, void* d_ws, size_t ws_size,
                              hipStream_t stream)
{
    const float* x    = (const float*)d_in[0];
    const float* Wi1  = (const float*)d_in[1];
    const float* Wh1  = (const float*)d_in[2];
    const float* b1   = (const float*)d_in[3];
    const float* Wi2  = (const float*)d_in[4];
    const float* Wh2  = (const float*)d_in[5];
    const float* b2   = (const float*)d_in[6];
    const float* Wlin = (const float*)d_in[7];
    const float* blin = (const float*)d_in[8];
    unsigned char* ws = (unsigned char*)d_ws;
    float* out = (float*)d_out;

    k_init<<<256, 256, 0, stream>>>(Wlin, ws);
    k_lstm<<<256, 512, 0, stream>>>(x, Wi1, Wh1, b1, Wi2, Wh2, b2, ws);
    k_out <<<256, 512, 0, stream>>>(ws, blin, out);
}